// Round 16
// baseline (93.604 us; speedup 1.0000x reference)
//
#include <hip/hip_runtime.h>
#include <math.h>
#include <stdint.h>

// n=256 samples, d=64, fp32 in/out. J-path bf16 MFMA.
//   K[m][l] = (1-h^2)[m] W1[m][l];  sKT[l][m] = K[m][l] (bf16), row 64 = h
//   W2sB[i][j][m] = bf16(W2[(i,j)][m] + W2[(j,i)][m])  (symmetric in i,j)
//   slab-frag af[t] and sKT-frag bf[t] are BOTH valid as A or B:
//     C1 = mfma(A=af[tr], B=bf[tc]) -> Ji[j][l];  C2 = mfma(A=bf[tr], B=af[tc])
//     -> Ji[l][j] at the SAME (lane,reg) => q in-register, no LDS transpose.
// Ledger: v7 512thr/128-VGPR spill-free (2 w/SIMD); v9 MFMA batching -2.9;
//   v10 pk-consume + 1-wave Jacobi -2.9; v11 W1T/b2s + 8x8 chains -2.3;
//   v12 net-zero; v13 DMA restored -0.5; v14 prologue/tail overlap -0.8;
//   v15 entry-DMA + pinned ext + Jacobi8 -0.2 (noise). ~52us of the 91.6
//   total is harness-fixed (fill+resets); conn ~35us, latency-bound.
// v16: distributed per-wave Jacobi — every wave redundantly solves the
//   64x64 system into its OWN szz copy (disjoint LDS, in-order DS per
//   wave): removes the final __syncthreads + drain and the t<64
//   divergence; out reads the wave-local z. Extra b2s/sg traffic is
//   replicated but L2/LDS-warm and pre-barrier-issued. Tail regs ~85<128.
//   PRE-COMMIT: |delta| < 0.8us => conn is at structural floor.

typedef short short8 __attribute__((ext_vector_type(8)));
typedef float f32x4 __attribute__((ext_vector_type(4)));
typedef float f32x2 __attribute__((ext_vector_type(2)));

__device__ __forceinline__ unsigned short f2bf(float f) {
  unsigned int u = __builtin_bit_cast(unsigned int, f);
  u += 0x7fffu + ((u >> 16) & 1u);
  return (unsigned short)(u >> 16);
}

__device__ __forceinline__ short8 as_short8(uint4 u) {
  union { uint4 a; short8 b; } cv; cv.a = u; return cv.b;
}

// DMA one 8KB slab (64 rows x 128B) global->LDS, 16B/lane/instr, 8 instrs.
// Source pre-swizzled so lds[row j][16B-slot s] = global(j, s ^ (j&7)).
__device__ __forceinline__ void stage_slab(const unsigned short* gslab,
                                           unsigned short* lbase, int lane) {
  const int srcoff = ((lane >> 3) << 6) + (((lane & 7) ^ (lane >> 3)) << 3);  // shorts
  const unsigned short* gsrc = gslab + srcoff;
  #pragma unroll
  for (int k = 0; k < 8; ++k) {
    __builtin_amdgcn_global_load_lds(
        (const __attribute__((address_space(1))) unsigned int*)(gsrc + (k << 9)),
        (__attribute__((address_space(3))) unsigned int*)(lbase + (k << 9)),
        16, 0, 0);
  }
}

// Blocks 0-127: W2sB (bf16 symmetrized W2 slabs). Block 128: W1T (f32).
// Block 129: b2s = b2 + b2^T (f32). All sample-invariant.
__global__ __launch_bounds__(256) void prep_kernel(
    const float* __restrict__ W2, const float* __restrict__ W1,
    const float* __restrict__ b2, unsigned short* __restrict__ W2sB,
    float* __restrict__ W1T, float* __restrict__ b2s) {
  const int b = blockIdx.x;
  if (b < 128) {
    int g = b * 256 + threadIdx.x;      // each thread: 8 consecutive m
    int i = g >> 9, j = (g >> 3) & 63, m8 = (g & 7) << 3;
    const float* pa = &W2[((((i << 6) + j) << 6) + m8)];
    const float* pb = &W2[((((j << 6) + i) << 6) + m8)];
    float4 a0 = *(const float4*)pa, a1 = *(const float4*)(pa + 4);
    float4 b0 = *(const float4*)pb, b1 = *(const float4*)(pb + 4);
    short8 r;
    r[0] = (short)f2bf(a0.x + b0.x); r[1] = (short)f2bf(a0.y + b0.y);
    r[2] = (short)f2bf(a0.z + b0.z); r[3] = (short)f2bf(a0.w + b0.w);
    r[4] = (short)f2bf(a1.x + b1.x); r[5] = (short)f2bf(a1.y + b1.y);
    r[6] = (short)f2bf(a1.z + b1.z); r[7] = (short)f2bf(a1.w + b1.w);
    *(short8*)&W2sB[(size_t)g << 3] = r;
  } else if (b == 128) {
    for (int e = threadIdx.x; e < 4096; e += 256) {
      int l = e >> 6, m = e & 63;
      W1T[e] = W1[(m << 6) + l];              // W1T[l][m] = W1[m][l]
    }
  } else {
    for (int e = threadIdx.x; e < 4096; e += 256) {
      int r = e >> 6, c = e & 63;
      b2s[e] = b2[(r << 6) + c] + b2[(c << 6) + r];
    }
  }
}

__global__ __launch_bounds__(512) void conn_kernel(
    const float* __restrict__ x, const float* __restrict__ v,
    const float* __restrict__ W1, const float* __restrict__ b1,
    const float* __restrict__ W3, const unsigned short* __restrict__ W2sB,
    const float* __restrict__ W1T, const float* __restrict__ b2s,
    float* __restrict__ out) {
  __shared__ __align__(16) unsigned short sAF[8][2][4096];  // per-wave slab dbuf, 128KB
  __shared__ __align__(16) unsigned short sKT[80 * 80];  // rows 0-63 = K^T, 64 = h, 65-79 = 0
  __shared__ __align__(16) float sg[64 * 68];            // g, stride 68 (f32x4-aligned stores)
  __shared__ __align__(16) float sh[64], sv[64], sx[64];

  const int n = blockIdx.x, t = threadIdx.x;
  const int wv = t >> 6, lane = t & 63, ln15 = lane & 15, quad = lane >> 4;
  const int o8 = t >> 3, s8 = t & 7;

  // Overlays into sKT rows 0-63 (bytes 0..10239): dead once bf frags are
  // pinned; ext reads use only rows 64-79 (bytes >= 10240).
  float* const spq = (float*)sKT;                      // [8][64] = 2048B
  float* const szz = (float*)sKT + 576 + (wv << 6);    // per-wave z, 8x[64]

  // ---- Issue slab-0 DMA FIRST: zero dependencies; its cold-HBM latency
  // (~900cy, L2 flushed by the harness fill) overlaps the whole prologue.
  unsigned short* const myAF = &sAF[wv][0][0];
  const unsigned short* const gbase = W2sB + ((size_t)(8 * wv) << 12);
  stage_slab(gbase, myAF, lane);   // slab 0 -> buf 0

  // ---- Early-issue all sample-invariant loads (complete by barrier 1's
  // vmcnt drain; latency overlaps the x/v hop). Regs die before i-loop.
  const float* w1r = &W1[(o8 << 6) + (s8 << 3)];
  float4 wa = *(const float4*)w1r, wb = *(const float4*)(w1r + 4);
  const int lL = t >> 3, m0 = (t & 7) << 3;          // sKT build: row lL, cols m0..m0+7
  float4 wt0 = *(const float4*)&W1T[(lL << 6) + m0];
  float4 wt1 = *(const float4*)&W1T[(lL << 6) + m0 + 4];
  const float b1v = b1[o8];

  if (t < 64) sx[t] = x[(n << 6) + t];
  else if (t < 128) sv[t - 64] = v[(n << 6) + (t - 64)];
  for (int e = t; e < 1280; e += 512) sKT[5120 + e] = 0;  // zero rows 64..79
  __syncthreads();

  // h[o] = tanh(b1[o] + sum_l sx[l] W1[o][l]); 8 lanes per output, shfl reduce
  {
    float4 xa = *(const float4*)&sx[s8 << 3], xb = *(const float4*)&sx[(s8 << 3) + 4];
    float acc = wa.x * xa.x + wa.y * xa.y + wa.z * xa.z + wa.w * xa.w
              + wb.x * xb.x + wb.y * xb.y + wb.z * xb.z + wb.w * xb.w;
    acc += __shfl_xor(acc, 1);
    acc += __shfl_xor(acc, 2);
    acc += __shfl_xor(acc, 4);
    if (s8 == 0) {
      float a = acc + b1v;
      a = fminf(10.f, fmaxf(-10.f, a));          // tanh(10)=1-4e-9, safe clamp
      float e2 = exp2f(a * 2.8853900817779268f); // e^(2a) via hw v_exp_f32
      sh[o8] = (e2 - 1.f) / (e2 + 1.f);
    }
  }
  __syncthreads();

  // sKT build: thread -> row lL, cols m0..m0+7; W1T chunk preloaded.
  {
    float4 h0 = *(const float4*)&sh[m0], h1 = *(const float4*)&sh[m0 + 4];
    short8 kk;
    kk[0] = (short)f2bf((1.f - h0.x * h0.x) * wt0.x);
    kk[1] = (short)f2bf((1.f - h0.y * h0.y) * wt0.y);
    kk[2] = (short)f2bf((1.f - h0.z * h0.z) * wt0.z);
    kk[3] = (short)f2bf((1.f - h0.w * h0.w) * wt0.w);
    kk[4] = (short)f2bf((1.f - h1.x * h1.x) * wt1.x);
    kk[5] = (short)f2bf((1.f - h1.y * h1.y) * wt1.y);
    kk[6] = (short)f2bf((1.f - h1.z * h1.z) * wt1.z);
    kk[7] = (short)f2bf((1.f - h1.w * h1.w) * wt1.w);
    *(short8*)&sKT[lL * 80 + m0] = kk;
  }
  if (t < 64) sKT[64 * 80 + t] = f2bf(sh[t]);
  __syncthreads();

  // sKT frags: tiles 0..3 dual-use (A for C2 row-tile / B for C1 col-tile).
  // Tile 4 (ext: h row) pinned in regs (+4 VGPR, -60 ds_reads/wave).
  short8 bf[4][2];
  #pragma unroll
  for (int tc = 0; tc < 4; ++tc)
    #pragma unroll
    for (int ks = 0; ks < 2; ++ks)
      bf[tc][ks] = *(const short8*)&sKT[(tc * 16 + ln15) * 80 + ks * 32 + quad * 8];
  const int extoff = (64 + ln15) * 80 + quad * 8;
  const short8 e0 = *(const short8*)&sKT[extoff];
  const short8 e1 = *(const short8*)&sKT[extoff + 32];

  f32x2 qacc2[4] = {{0.f, 0.f}, {0.f, 0.f}, {0.f, 0.f}, {0.f, 0.f}};

  // Wave wv owns i in [8*wv, 8*wv+8). Slab frags from LDS, swizzled reads:
  // element slot' = slot ^ (ln15&7); af[tc][1] address = [0] address ^ 32.
  const int f0 = (ln15 << 6) + (((quad ^ ln15) & 7) << 3);

  #pragma unroll 1
  for (int ii = 0; ii < 8; ++ii) {
    asm volatile("s_waitcnt vmcnt(0)" ::: "memory");   // buf[ii&1] DMA complete
    __builtin_amdgcn_sched_barrier(0);
    if (ii < 7)  // prefetch next slab into the other buffer; flies across compute
      stage_slab(gbase + ((size_t)(ii + 1) << 12), myAF + (((ii & 1) ^ 1) << 12), lane);

    const unsigned short* buf = myAF + ((ii & 1) << 12);
    uint4 af[4][2];
    #pragma unroll
    for (int tc = 0; tc < 4; ++tc) {
      af[tc][0] = *(const uint4*)&buf[(tc << 10) + f0];
      af[tc][1] = *(const uint4*)&buf[(tc << 10) + (f0 ^ 32)];
    }
    const int i = 8 * wv + ii;
    const float vi = sv[i];

    #pragma unroll
    for (int tr = 0; tr < 4; ++tr) {
      short8 a0 = as_short8(af[tr][0]), a1 = as_short8(af[tr][1]);
      // Batch all 8 independent 2-deep MFMA chains before any VALU consume:
      // cross-tc ILP hides MFMA latency.
      f32x4 c1[4], c2[4];
      #pragma unroll
      for (int tc = 0; tc < 4; ++tc) {
        f32x4 z4 = {0.f, 0.f, 0.f, 0.f};
        f32x4 u = __builtin_amdgcn_mfma_f32_16x16x32_bf16(a0, bf[tc][0], z4, 0, 0, 0);
        c1[tc]  = __builtin_amdgcn_mfma_f32_16x16x32_bf16(a1, bf[tc][1], u, 0, 0, 0);
        f32x4 w = __builtin_amdgcn_mfma_f32_16x16x32_bf16(bf[tr][0], as_short8(af[tc][0]), z4, 0, 0, 0);
        c2[tc]  = __builtin_amdgcn_mfma_f32_16x16x32_bf16(bf[tr][1], as_short8(af[tc][1]), w, 0, 0, 0);
      }
      {
        f32x4 z4 = {0.f, 0.f, 0.f, 0.f};
        f32x4 u  = __builtin_amdgcn_mfma_f32_16x16x32_bf16(a0, e0, z4, 0, 0, 0);
        f32x4 ce = __builtin_amdgcn_mfma_f32_16x16x32_bf16(a1, e1, u, 0, 0, 0);
        if (ln15 == 0)  // g[i][j], j = 16*tr + 4*quad + r
          *(f32x4*)&sg[i * 68 + tr * 16 + quad * 4] = ce;
      }
      // Packed-fp32 consume: per tc 6 pk ops, fma folded into qacc2.
      f32x4 svj = *(const f32x4*)&sv[tr * 16 + quad * 4];
      f32x2 vi2 = {vi, vi};
      f32x2 w01 = f32x2{svj[0], svj[1]} * vi2;
      f32x2 w23 = f32x2{svj[2], svj[3]} * vi2;
      #pragma unroll
      for (int tc = 0; tc < 4; ++tc) {
        f32x2 c101 = {c1[tc][0], c1[tc][1]}, c123 = {c1[tc][2], c1[tc][3]};
        f32x2 c201 = {c2[tc][0], c2[tc][1]}, c223 = {c2[tc][2], c2[tc][3]};
        f32x2 t01 = (c101 * c101) * c201;
        f32x2 t23 = (c123 * c123) * c223;
        qacc2[tc] = __builtin_elementwise_fma(t01, w01, qacc2[tc]);
        qacc2[tc] = __builtin_elementwise_fma(t23, w23, qacc2[tc]);
      }
    }
  }

  // reduce qacc over quads (rows j), publish per-wave partial q.
  // spq overlays sKT rows 0-63: dead for ALL waves during/after the i-loop
  // (only rows 64-79 are read as ext frags), so no barrier needed first.
  #pragma unroll
  for (int tc = 0; tc < 4; ++tc) {
    float s = qacc2[tc][0] + qacc2[tc][1];
    s += __shfl_xor(s, 16, 64);
    s += __shfl_xor(s, 32, 64);
    if (quad == 0) spq[(wv << 6) + tc * 16 + ln15] = s;
  }

  // Hoisted output operands: accv = v @ W3[o8][:64]; wda/wdb = W3[o8][64:]
  // held across Jacobi (i-loop regs dead). Overlaps W3 L2 latency.
  float accv;
  float4 wda, wdb;
  {
    const float* w3r = &W3[o8 << 7];
    float4 wva = *(const float4*)&w3r[s8 << 3];
    float4 wvb = *(const float4*)&w3r[(s8 << 3) + 4];
    wda = *(const float4*)&w3r[64 + (s8 << 3)];
    wdb = *(const float4*)&w3r[64 + (s8 << 3) + 4];
    float4 va = *(const float4*)&sv[s8 << 3], vb = *(const float4*)&sv[(s8 << 3) + 4];
    accv = wva.x * va.x + wva.y * va.y + wva.z * va.z + wva.w * va.w
         + wvb.x * vb.x + wvb.y * vb.y + wvb.z * vb.z + wvb.w * vb.w;
  }

  // v16: EVERY wave pre-loads the b2s row for its `lane` BEFORE the
  // barrier (replicated, L2-warm, latency hides under arrival + drain).
  f32x4 gr[16];
  float b2diag;
  {
    const float* b2row = &b2s[lane << 6];
    #pragma unroll
    for (int cc = 0; cc < 16; ++cc) gr[cc] = *(const f32x4*)&b2row[cc << 2];
    b2diag = b2row[lane];
  }
  __syncthreads();  // first block-wide sync since setup; sg/spq now visible

  // v16: distributed Jacobi — all 8 waves redundantly solve the 64x64
  // system into their own szz copy (disjoint LDS; in-order DS per wave).
  // No final barrier: out reads the wave-local z. 8 iters: rho~0.27 =>
  // residual ~3e-5 << bf16-J quantization floor ~1e-3.
  {
    const float* grow = &sg[lane * 68];
    #pragma unroll
    for (int cc = 0; cc < 16; ++cc) {
      f32x4 s4 = *(const f32x4*)&grow[cc << 2];
      gr[cc] += s4;
    }
    float q = spq[lane] + spq[64 + lane] + spq[128 + lane] + spq[192 + lane]
            + spq[256 + lane] + spq[320 + lane] + spq[384 + lane] + spq[448 + lane];
    const float dinv = 1.f / (grow[lane] + b2diag);
    float zr = q * dinv;
    szz[lane] = zr;
    #pragma unroll 1
    for (int it = 0; it < 8; ++it) {
      float p[8];
      #pragma unroll
      for (int cc = 0; cc < 8; ++cc) {
        f32x4 za_ = *(const f32x4*)&szz[cc << 3];
        f32x4 zb_ = *(const f32x4*)&szz[(cc << 3) + 4];
        f32x4 ga = gr[cc << 1], gb = gr[(cc << 1) + 1];
        float s = ga[0] * za_[0];
        s = fmaf(ga[1], za_[1], s);
        s = fmaf(ga[2], za_[2], s);
        s = fmaf(ga[3], za_[3], s);
        s = fmaf(gb[0], zb_[0], s);
        s = fmaf(gb[1], zb_[1], s);
        s = fmaf(gb[2], zb_[2], s);
        s = fmaf(gb[3], zb_[3], s);
        p[cc] = s;
      }
      float r4 = ((p[0] + p[1]) + (p[2] + p[3])) + ((p[4] + p[5]) + (p[6] + p[7]));
      zr = zr + (q - r4) * dinv;
      szz[lane] = zr;
      __builtin_amdgcn_sched_barrier(0);
    }
  }
  // No barrier: each wave reads its own szz copy below.

  // out[o] = accv + 0.5 * sum_c z[c] W3[o][64+c]; 8 lanes/row, wave-local z
  {
    float4 za = *(const float4*)&szz[s8 << 3], zb = *(const float4*)&szz[(s8 << 3) + 4];
    float acc = accv
              + 0.5f * (wda.x * za.x + wda.y * za.y + wda.z * za.z + wda.w * za.w
                      + wdb.x * zb.x + wdb.y * zb.y + wdb.z * zb.z + wdb.w * zb.w);
    acc += __shfl_xor(acc, 1);
    acc += __shfl_xor(acc, 2);
    acc += __shfl_xor(acc, 4);
    if (s8 == 0) out[(n << 6) + o8] = acc;
  }
}

extern "C" void kernel_launch(void* const* d_in, const int* in_sizes, int n_in,
                              void* d_out, int out_size, void* d_ws, size_t ws_size,
                              hipStream_t stream) {
  (void)in_sizes; (void)n_in; (void)out_size; (void)ws_size;
  const float* x  = (const float*)d_in[1];
  const float* v  = (const float*)d_in[2];
  const float* W1 = (const float*)d_in[3];
  const float* b1 = (const float*)d_in[4];
  const float* W2 = (const float*)d_in[5];
  const float* b2 = (const float*)d_in[6];
  const float* W3 = (const float*)d_in[7];
  unsigned short* W2sB = (unsigned short*)d_ws;       // 64*64*64 bf16 = 512 KB
  float* W1T = (float*)((char*)d_ws + (512 << 10));   // 16 KB
  float* b2s = W1T + 4096;                            // 16 KB

  hipLaunchKernelGGL(prep_kernel, dim3(130), dim3(256), 0, stream,
                     W2, W1, b2, W2sB, W1T, b2s);
  hipLaunchKernelGGL(conn_kernel, dim3(256), dim3(512), 0, stream,
                     x, v, W1, b1, W3, W2sB, W1T, b2s, (float*)d_out);
}

// Round 17
// 91.641 us; speedup vs baseline: 1.0214x; 1.0214x over previous
//
#include <hip/hip_runtime.h>
#include <math.h>
#include <stdint.h>

// n=256 samples, d=64, fp32 in/out. J-path bf16 MFMA.
//   K[m][l] = (1-h^2)[m] W1[m][l];  sKT[l][m] = K[m][l] (bf16), row 64 = h
//   W2sB[i][j][m] = bf16(W2[(i,j)][m] + W2[(j,i)][m])  (symmetric in i,j)
//   slab-frag af[t] and sKT-frag bf[t] are BOTH valid as A or B:
//     C1 = mfma(A=af[tr], B=bf[tc]) -> Ji[j][l];  C2 = mfma(A=bf[tr], B=af[tc])
//     -> Ji[l][j] at the SAME (lane,reg) => q in-register, no LDS transpose.
// Ledger: v7 512thr/128-VGPR spill-free (2 w/SIMD); v9 MFMA batching -2.9;
//   v10 pk-consume + 1-wave Jacobi -2.9; v11 W1T/b2s + 8x8 chains -2.3;
//   v12 net-zero; v13 DMA restored -0.5; v14 prologue/tail overlap -0.8;
//   v15 entry-DMA + pinned ext + Jacobi8 -0.2; v16 distributed per-wave
//   Jacobi REGRESSED +2.0 (8x replicated solve traffic >> one barrier:
//   redundant-compute-for-barrier only pays when the work is trivial).
// v17 = v15 verbatim (best verified: 91.61us). Floor model: conn ~35us =
//   i-loop MFMA ~7 + VALU ~5 + slab L2 ~4 + serial prologue/tail ~8 +
//   cold-L2/ramp; remaining ~56us of dur_us is harness-fixed (40us fill +
//   resets + gaps), unreachable from kernel source.

typedef short short8 __attribute__((ext_vector_type(8)));
typedef float f32x4 __attribute__((ext_vector_type(4)));
typedef float f32x2 __attribute__((ext_vector_type(2)));

__device__ __forceinline__ unsigned short f2bf(float f) {
  unsigned int u = __builtin_bit_cast(unsigned int, f);
  u += 0x7fffu + ((u >> 16) & 1u);
  return (unsigned short)(u >> 16);
}

__device__ __forceinline__ short8 as_short8(uint4 u) {
  union { uint4 a; short8 b; } cv; cv.a = u; return cv.b;
}

// DMA one 8KB slab (64 rows x 128B) global->LDS, 16B/lane/instr, 8 instrs.
// Source pre-swizzled so lds[row j][16B-slot s] = global(j, s ^ (j&7)).
__device__ __forceinline__ void stage_slab(const unsigned short* gslab,
                                           unsigned short* lbase, int lane) {
  const int srcoff = ((lane >> 3) << 6) + (((lane & 7) ^ (lane >> 3)) << 3);  // shorts
  const unsigned short* gsrc = gslab + srcoff;
  #pragma unroll
  for (int k = 0; k < 8; ++k) {
    __builtin_amdgcn_global_load_lds(
        (const __attribute__((address_space(1))) unsigned int*)(gsrc + (k << 9)),
        (__attribute__((address_space(3))) unsigned int*)(lbase + (k << 9)),
        16, 0, 0);
  }
}

// Blocks 0-127: W2sB (bf16 symmetrized W2 slabs). Block 128: W1T (f32).
// Block 129: b2s = b2 + b2^T (f32). All sample-invariant.
__global__ __launch_bounds__(256) void prep_kernel(
    const float* __restrict__ W2, const float* __restrict__ W1,
    const float* __restrict__ b2, unsigned short* __restrict__ W2sB,
    float* __restrict__ W1T, float* __restrict__ b2s) {
  const int b = blockIdx.x;
  if (b < 128) {
    int g = b * 256 + threadIdx.x;      // each thread: 8 consecutive m
    int i = g >> 9, j = (g >> 3) & 63, m8 = (g & 7) << 3;
    const float* pa = &W2[((((i << 6) + j) << 6) + m8)];
    const float* pb = &W2[((((j << 6) + i) << 6) + m8)];
    float4 a0 = *(const float4*)pa, a1 = *(const float4*)(pa + 4);
    float4 b0 = *(const float4*)pb, b1 = *(const float4*)(pb + 4);
    short8 r;
    r[0] = (short)f2bf(a0.x + b0.x); r[1] = (short)f2bf(a0.y + b0.y);
    r[2] = (short)f2bf(a0.z + b0.z); r[3] = (short)f2bf(a0.w + b0.w);
    r[4] = (short)f2bf(a1.x + b1.x); r[5] = (short)f2bf(a1.y + b1.y);
    r[6] = (short)f2bf(a1.z + b1.z); r[7] = (short)f2bf(a1.w + b1.w);
    *(short8*)&W2sB[(size_t)g << 3] = r;
  } else if (b == 128) {
    for (int e = threadIdx.x; e < 4096; e += 256) {
      int l = e >> 6, m = e & 63;
      W1T[e] = W1[(m << 6) + l];              // W1T[l][m] = W1[m][l]
    }
  } else {
    for (int e = threadIdx.x; e < 4096; e += 256) {
      int r = e >> 6, c = e & 63;
      b2s[e] = b2[(r << 6) + c] + b2[(c << 6) + r];
    }
  }
}

__global__ __launch_bounds__(512) void conn_kernel(
    const float* __restrict__ x, const float* __restrict__ v,
    const float* __restrict__ W1, const float* __restrict__ b1,
    const float* __restrict__ W3, const unsigned short* __restrict__ W2sB,
    const float* __restrict__ W1T, const float* __restrict__ b2s,
    float* __restrict__ out) {
  __shared__ __align__(16) unsigned short sAF[8][2][4096];  // per-wave slab dbuf, 128KB
  __shared__ __align__(16) unsigned short sKT[80 * 80];  // rows 0-63 = K^T, 64 = h, 65-79 = 0
  __shared__ __align__(16) float sg[64 * 68];            // g, stride 68 (f32x4-aligned stores)
  __shared__ __align__(16) float sh[64], sv[64], sx[64];

  // Overlays into sKT rows 0-63 (bytes 0..10239): dead once bf frags are
  // pinned; ext reads use only rows 64-79 (bytes >= 10240).
  float* const spq = (float*)sKT;          // [8][64] = 2048B
  float* const szz = (float*)sKT + 576;    // [64] = 256B (z vector)

  const int n = blockIdx.x, t = threadIdx.x;
  const int wv = t >> 6, lane = t & 63, ln15 = lane & 15, quad = lane >> 4;
  const int o8 = t >> 3, s8 = t & 7;

  // ---- Issue slab-0 DMA FIRST: zero dependencies; its cold-HBM latency
  // (~900cy, L2 flushed by the harness fill) overlaps the whole prologue.
  unsigned short* const myAF = &sAF[wv][0][0];
  const unsigned short* const gbase = W2sB + ((size_t)(8 * wv) << 12);
  stage_slab(gbase, myAF, lane);   // slab 0 -> buf 0

  // ---- Early-issue all sample-invariant loads (complete by barrier 1's
  // vmcnt drain; latency overlaps the x/v hop). Regs die before i-loop.
  const float* w1r = &W1[(o8 << 6) + (s8 << 3)];
  float4 wa = *(const float4*)w1r, wb = *(const float4*)(w1r + 4);
  const int lL = t >> 3, m0 = (t & 7) << 3;          // sKT build: row lL, cols m0..m0+7
  float4 wt0 = *(const float4*)&W1T[(lL << 6) + m0];
  float4 wt1 = *(const float4*)&W1T[(lL << 6) + m0 + 4];
  const float b1v = b1[o8];

  if (t < 64) sx[t] = x[(n << 6) + t];
  else if (t < 128) sv[t - 64] = v[(n << 6) + (t - 64)];
  for (int e = t; e < 1280; e += 512) sKT[5120 + e] = 0;  // zero rows 64..79
  __syncthreads();

  // h[o] = tanh(b1[o] + sum_l sx[l] W1[o][l]); 8 lanes per output, shfl reduce
  {
    float4 xa = *(const float4*)&sx[s8 << 3], xb = *(const float4*)&sx[(s8 << 3) + 4];
    float acc = wa.x * xa.x + wa.y * xa.y + wa.z * xa.z + wa.w * xa.w
              + wb.x * xb.x + wb.y * xb.y + wb.z * xb.z + wb.w * xb.w;
    acc += __shfl_xor(acc, 1);
    acc += __shfl_xor(acc, 2);
    acc += __shfl_xor(acc, 4);
    if (s8 == 0) {
      float a = acc + b1v;
      a = fminf(10.f, fmaxf(-10.f, a));          // tanh(10)=1-4e-9, safe clamp
      float e2 = exp2f(a * 2.8853900817779268f); // e^(2a) via hw v_exp_f32
      sh[o8] = (e2 - 1.f) / (e2 + 1.f);
    }
  }
  __syncthreads();

  // sKT build: thread -> row lL, cols m0..m0+7; W1T chunk preloaded.
  {
    float4 h0 = *(const float4*)&sh[m0], h1 = *(const float4*)&sh[m0 + 4];
    short8 kk;
    kk[0] = (short)f2bf((1.f - h0.x * h0.x) * wt0.x);
    kk[1] = (short)f2bf((1.f - h0.y * h0.y) * wt0.y);
    kk[2] = (short)f2bf((1.f - h0.z * h0.z) * wt0.z);
    kk[3] = (short)f2bf((1.f - h0.w * h0.w) * wt0.w);
    kk[4] = (short)f2bf((1.f - h1.x * h1.x) * wt1.x);
    kk[5] = (short)f2bf((1.f - h1.y * h1.y) * wt1.y);
    kk[6] = (short)f2bf((1.f - h1.z * h1.z) * wt1.z);
    kk[7] = (short)f2bf((1.f - h1.w * h1.w) * wt1.w);
    *(short8*)&sKT[lL * 80 + m0] = kk;
  }
  if (t < 64) sKT[64 * 80 + t] = f2bf(sh[t]);
  __syncthreads();

  // sKT frags: tiles 0..3 dual-use (A for C2 row-tile / B for C1 col-tile).
  // Tile 4 (ext: h row) pinned in regs (+4 VGPR, -60 ds_reads/wave).
  short8 bf[4][2];
  #pragma unroll
  for (int tc = 0; tc < 4; ++tc)
    #pragma unroll
    for (int ks = 0; ks < 2; ++ks)
      bf[tc][ks] = *(const short8*)&sKT[(tc * 16 + ln15) * 80 + ks * 32 + quad * 8];
  const int extoff = (64 + ln15) * 80 + quad * 8;
  const short8 e0 = *(const short8*)&sKT[extoff];
  const short8 e1 = *(const short8*)&sKT[extoff + 32];

  f32x2 qacc2[4] = {{0.f, 0.f}, {0.f, 0.f}, {0.f, 0.f}, {0.f, 0.f}};

  // Wave wv owns i in [8*wv, 8*wv+8). Slab frags from LDS, swizzled reads:
  // element slot' = slot ^ (ln15&7); af[tc][1] address = [0] address ^ 32.
  const int f0 = (ln15 << 6) + (((quad ^ ln15) & 7) << 3);

  #pragma unroll 1
  for (int ii = 0; ii < 8; ++ii) {
    asm volatile("s_waitcnt vmcnt(0)" ::: "memory");   // buf[ii&1] DMA complete
    __builtin_amdgcn_sched_barrier(0);
    if (ii < 7)  // prefetch next slab into the other buffer; flies across compute
      stage_slab(gbase + ((size_t)(ii + 1) << 12), myAF + (((ii & 1) ^ 1) << 12), lane);

    const unsigned short* buf = myAF + ((ii & 1) << 12);
    uint4 af[4][2];
    #pragma unroll
    for (int tc = 0; tc < 4; ++tc) {
      af[tc][0] = *(const uint4*)&buf[(tc << 10) + f0];
      af[tc][1] = *(const uint4*)&buf[(tc << 10) + (f0 ^ 32)];
    }
    const int i = 8 * wv + ii;
    const float vi = sv[i];

    #pragma unroll
    for (int tr = 0; tr < 4; ++tr) {
      short8 a0 = as_short8(af[tr][0]), a1 = as_short8(af[tr][1]);
      // Batch all 8 independent 2-deep MFMA chains before any VALU consume:
      // cross-tc ILP hides MFMA latency.
      f32x4 c1[4], c2[4];
      #pragma unroll
      for (int tc = 0; tc < 4; ++tc) {
        f32x4 z4 = {0.f, 0.f, 0.f, 0.f};
        f32x4 u = __builtin_amdgcn_mfma_f32_16x16x32_bf16(a0, bf[tc][0], z4, 0, 0, 0);
        c1[tc]  = __builtin_amdgcn_mfma_f32_16x16x32_bf16(a1, bf[tc][1], u, 0, 0, 0);
        f32x4 w = __builtin_amdgcn_mfma_f32_16x16x32_bf16(bf[tr][0], as_short8(af[tc][0]), z4, 0, 0, 0);
        c2[tc]  = __builtin_amdgcn_mfma_f32_16x16x32_bf16(bf[tr][1], as_short8(af[tc][1]), w, 0, 0, 0);
      }
      {
        f32x4 z4 = {0.f, 0.f, 0.f, 0.f};
        f32x4 u  = __builtin_amdgcn_mfma_f32_16x16x32_bf16(a0, e0, z4, 0, 0, 0);
        f32x4 ce = __builtin_amdgcn_mfma_f32_16x16x32_bf16(a1, e1, u, 0, 0, 0);
        if (ln15 == 0)  // g[i][j], j = 16*tr + 4*quad + r
          *(f32x4*)&sg[i * 68 + tr * 16 + quad * 4] = ce;
      }
      // Packed-fp32 consume: per tc 6 pk ops, fma folded into qacc2.
      f32x4 svj = *(const f32x4*)&sv[tr * 16 + quad * 4];
      f32x2 vi2 = {vi, vi};
      f32x2 w01 = f32x2{svj[0], svj[1]} * vi2;
      f32x2 w23 = f32x2{svj[2], svj[3]} * vi2;
      #pragma unroll
      for (int tc = 0; tc < 4; ++tc) {
        f32x2 c101 = {c1[tc][0], c1[tc][1]}, c123 = {c1[tc][2], c1[tc][3]};
        f32x2 c201 = {c2[tc][0], c2[tc][1]}, c223 = {c2[tc][2], c2[tc][3]};
        f32x2 t01 = (c101 * c101) * c201;
        f32x2 t23 = (c123 * c123) * c223;
        qacc2[tc] = __builtin_elementwise_fma(t01, w01, qacc2[tc]);
        qacc2[tc] = __builtin_elementwise_fma(t23, w23, qacc2[tc]);
      }
    }
  }

  // reduce qacc over quads (rows j), publish per-wave partial q.
  // spq overlays sKT rows 0-63: dead for ALL waves during/after the i-loop
  // (only rows 64-79 are read as ext frags), so no barrier needed first.
  #pragma unroll
  for (int tc = 0; tc < 4; ++tc) {
    float s = qacc2[tc][0] + qacc2[tc][1];
    s += __shfl_xor(s, 16, 64);
    s += __shfl_xor(s, 32, 64);
    if (quad == 0) spq[(wv << 6) + tc * 16 + ln15] = s;
  }

  // Hoisted output operands: accv = v @ W3[o8][:64]; wda/wdb = W3[o8][64:]
  // held across Jacobi (i-loop regs dead). Overlaps W3 L2 latency.
  float accv;
  float4 wda, wdb;
  {
    const float* w3r = &W3[o8 << 7];
    float4 wva = *(const float4*)&w3r[s8 << 3];
    float4 wvb = *(const float4*)&w3r[(s8 << 3) + 4];
    wda = *(const float4*)&w3r[64 + (s8 << 3)];
    wdb = *(const float4*)&w3r[64 + (s8 << 3) + 4];
    float4 va = *(const float4*)&sv[s8 << 3], vb = *(const float4*)&sv[(s8 << 3) + 4];
    accv = wva.x * va.x + wva.y * va.y + wva.z * va.z + wva.w * va.w
         + wvb.x * vb.x + wvb.y * vb.y + wvb.z * vb.z + wvb.w * vb.w;
  }

  // Jacobi wave pre-loads its b2s row BEFORE the barrier: the 16 f32x4
  // global loads complete during barrier arrival + vmcnt drain.
  f32x4 gr[16];
  float b2diag = 0.f;
  if (t < 64) {
    const float* b2row = &b2s[t << 6];
    #pragma unroll
    for (int cc = 0; cc < 16; ++cc) gr[cc] = *(const f32x4*)&b2row[cc << 2];
    b2diag = b2row[t];
  }
  __syncthreads();  // first block-wide sync since setup; sg/spq now visible

  // Jacobi: z' = z + (q - g z)/diag, g = sg + b2s (b2s folded into gr).
  // Single-wave register-matvec: lane r holds g-row r; z in LDS broadcast.
  // 8 independent 8-deep fma chains; NO per-iter drain (in-wave DS is
  // in-order). 8 iters: rho(D^-1 E)~0.27 => residual ~3e-5 << bf16-J
  // quantization floor ~1e-3. absmax is the tripwire.
  if (t < 64) {
    const float* grow = &sg[t * 68];
    #pragma unroll
    for (int cc = 0; cc < 16; ++cc) {
      f32x4 s4 = *(const f32x4*)&grow[cc << 2];
      gr[cc] += s4;
    }
    float q = spq[t] + spq[64 + t] + spq[128 + t] + spq[192 + t]
            + spq[256 + t] + spq[320 + t] + spq[384 + t] + spq[448 + t];
    const float dinv = 1.f / (grow[t] + b2diag);
    float zr = q * dinv;
    szz[t] = zr;
    #pragma unroll 1
    for (int it = 0; it < 8; ++it) {
      float p[8];
      #pragma unroll
      for (int cc = 0; cc < 8; ++cc) {
        f32x4 za_ = *(const f32x4*)&szz[cc << 3];
        f32x4 zb_ = *(const f32x4*)&szz[(cc << 3) + 4];
        f32x4 ga = gr[cc << 1], gb = gr[(cc << 1) + 1];
        float s = ga[0] * za_[0];
        s = fmaf(ga[1], za_[1], s);
        s = fmaf(ga[2], za_[2], s);
        s = fmaf(ga[3], za_[3], s);
        s = fmaf(gb[0], zb_[0], s);
        s = fmaf(gb[1], zb_[1], s);
        s = fmaf(gb[2], zb_[2], s);
        s = fmaf(gb[3], zb_[3], s);
        p[cc] = s;
      }
      float r4 = ((p[0] + p[1]) + (p[2] + p[3])) + ((p[4] + p[5]) + (p[6] + p[7]));
      zr = zr + (q - r4) * dinv;
      szz[t] = zr;
      __builtin_amdgcn_sched_barrier(0);
    }
  }
  __syncthreads();

  // out[o] = accv + 0.5 * sum_c z[c] W3[o][64+c]; 8 lanes/row
  {
    float4 za = *(const float4*)&szz[s8 << 3], zb = *(const float4*)&szz[(s8 << 3) + 4];
    float acc = accv
              + 0.5f * (wda.x * za.x + wda.y * za.y + wda.z * za.z + wda.w * za.w
                      + wdb.x * zb.x + wdb.y * zb.y + wdb.z * zb.z + wdb.w * zb.w);
    acc += __shfl_xor(acc, 1);
    acc += __shfl_xor(acc, 2);
    acc += __shfl_xor(acc, 4);
    if (s8 == 0) out[(n << 6) + o8] = acc;
  }
}

extern "C" void kernel_launch(void* const* d_in, const int* in_sizes, int n_in,
                              void* d_out, int out_size, void* d_ws, size_t ws_size,
                              hipStream_t stream) {
  (void)in_sizes; (void)n_in; (void)out_size; (void)ws_size;
  const float* x  = (const float*)d_in[1];
  const float* v  = (const float*)d_in[2];
  const float* W1 = (const float*)d_in[3];
  const float* b1 = (const float*)d_in[4];
  const float* W2 = (const float*)d_in[5];
  const float* b2 = (const float*)d_in[6];
  const float* W3 = (const float*)d_in[7];
  unsigned short* W2sB = (unsigned short*)d_ws;       // 64*64*64 bf16 = 512 KB
  float* W1T = (float*)((char*)d_ws + (512 << 10));   // 16 KB
  float* b2s = W1T + 4096;                            // 16 KB

  hipLaunchKernelGGL(prep_kernel, dim3(130), dim3(256), 0, stream,
                     W2, W1, b2, W2sB, W1T, b2s);
  hipLaunchKernelGGL(conn_kernel, dim3(256), dim3(512), 0, stream,
                     x, v, W1, b1, W3, W2sB, W1T, b2s, (float*)d_out);
}